// Round 2
// baseline (391.625 us; speedup 1.0000x reference)
//
#include <hip/hip_runtime.h>
#include <math.h>

#define NTHR 256

struct Params {
    const float* x;
    const int*   samp1;
    const int*   samp2;
    const int*   samp3;
    const float* pe_w; const float* pe_b;
    const float* qw; const float* qb;
    const float* kw; const float* kb;
    const float* vw; const float* vb;
    const float* ow; const float* ob;
    const float* f1w; const float* f1b;
    const float* f2w; const float* f2b;
    const float* ln1g; const float* ln1b;
    const float* ln2g; const float* ln2b;
    const float* sp1w1; const float* sp1b1; const float* sp1w2; const float* sp1b2;
    const float* sp2w1; const float* sp2b1; const float* sp2w2; const float* sp2b2;
    const float* dr_w; const float* dr_b;
    const float* fc1w; const float* fc1b;
    const float* fc2w; const float* fc2b;
    const float* fow;  const float* fob;
    const float* scale;   // ws: (max - min + 1e-6)
    float* out;
};

__global__ __launch_bounds__(256) void minmax_part(const float4* __restrict__ x4, int n4,
                                                   float* __restrict__ part) {
    float mx = -INFINITY, mn = INFINITY;
    for (int i = blockIdx.x * blockDim.x + threadIdx.x; i < n4; i += gridDim.x * blockDim.x) {
        float4 v = x4[i];
        mx = fmaxf(fmaxf(fmaxf(mx, v.x), fmaxf(v.y, v.z)), v.w);
        mn = fminf(fminf(fminf(mn, v.x), fminf(v.y, v.z)), v.w);
    }
#pragma unroll
    for (int o = 32; o; o >>= 1) {
        mx = fmaxf(mx, __shfl_xor(mx, o));
        mn = fminf(mn, __shfl_xor(mn, o));
    }
    __shared__ float smx[4], smn[4];
    if ((threadIdx.x & 63) == 0) { smx[threadIdx.x >> 6] = mx; smn[threadIdx.x >> 6] = mn; }
    __syncthreads();
    if (threadIdx.x == 0) {
        for (int w = 1; w < 4; ++w) { mx = fmaxf(mx, smx[w]); mn = fminf(mn, smn[w]); }
        part[blockIdx.x * 2]     = mx;
        part[blockIdx.x * 2 + 1] = mn;
    }
}

__global__ __launch_bounds__(256) void minmax_final(const float* __restrict__ part, int nb,
                                                    float* __restrict__ scale) {
    float mx = -INFINITY, mn = INFINITY;
    for (int i = threadIdx.x; i < nb; i += blockDim.x) {
        mx = fmaxf(mx, part[2 * i]);
        mn = fminf(mn, part[2 * i + 1]);
    }
#pragma unroll
    for (int o = 32; o; o >>= 1) {
        mx = fmaxf(mx, __shfl_xor(mx, o));
        mn = fminf(mn, __shfl_xor(mn, o));
    }
    __shared__ float smx[4], smn[4];
    if ((threadIdx.x & 63) == 0) { smx[threadIdx.x >> 6] = mx; smn[threadIdx.x >> 6] = mn; }
    __syncthreads();
    if (threadIdx.x == 0) {
        for (int w = 1; w < 4; ++w) { mx = fmaxf(mx, smx[w]); mn = fminf(mn, smn[w]); }
        scale[0] = mx - mn + 1e-6f;
    }
}

// One block per batch sample. All intermediates in LDS (rows padded to 9 floats:
// stride 9 is odd -> bijective mod 32 banks -> conflict-free row-wise access).
__global__ __launch_bounds__(256) void fused_forward(Params p) {
    const int b = blockIdx.x;
    const int t = threadIdx.x;

    __shared__ float h [148 * 9];
    __shared__ float qs[148 * 9];
    __shared__ float ks[148 * 9];
    __shared__ float vs[148 * 9];
    __shared__ float sc[25 * 149];     // scores; also reused (as int*) to stage samp
    __shared__ float Mv_unused[4];     // keep layout simple (unused)
    __shared__ float ssp[148];
    __shared__ float headf[148];
    __shared__ float upd[25 * 9];
    __shared__ float smax[25], ssum[25];
    __shared__ float vmean[8];
    __shared__ unsigned long long keys[148];
    __shared__ int   topi[25];
    __shared__ int   sel[148];
    __shared__ int   ntop;
    __shared__ float hd2[37];          // head fc2 output

    (void)Mv_unused;
    const float dscale = p.scale[0];

    // ---- preprocess: pair-mean of [x, x/scale], concat sin/cos pe, @pe_w + pe_b
    if (t < 148) {
        const float2 xp = ((const float2*)(p.x + b * 296))[t];
        float pin[4];
        pin[0] = 0.5f * (xp.x + xp.y);
        pin[1] = 0.5f * (xp.x / dscale + xp.y / dscale);
        pin[2] = sinf((float)t);
        pin[3] = cosf((float)t);
#pragma unroll
        for (int dd = 0; dd < 8; ++dd) {
            float acc = 0.f;
#pragma unroll
            for (int e = 0; e < 4; ++e) acc += pin[e] * p.pe_w[e * 8 + dd];
            h[t * 9 + dd] = acc + p.pe_b[dd];
        }
    }
    __syncthreads();

    int L = 148;
    for (int layer = 0; layer < 3; ++layer) {
        const float* qw = p.qw + layer * 64;  const float* qb = p.qb + layer * 8;
        const float* kw = p.kw + layer * 64;  const float* kb = p.kb + layer * 8;
        const float* vw = p.vw + layer * 64;  const float* vb = p.vb + layer * 8;
        const float* ow = p.ow + layer * 64;  const float* ob = p.ob + layer * 8;
        const float* f1w = p.f1w + layer * 96; const float* f1b = p.f1b + layer * 12;
        const float* f2w = p.f2w + layer * 96; const float* f2b = p.f2b + layer * 8;
        const float* g1 = p.ln1g + layer * 8; const float* bb1 = p.ln1b + layer * 8;
        const float* g2 = p.ln2g + layer * 8; const float* bb2 = p.ln2b + layer * 8;
        const int* samp = (layer == 0) ? p.samp1 : (layer == 1) ? p.samp2 : p.samp3;
        const int usamp = (layer == 2) ? 20 : 25;
        const int u     = (layer == 2) ? 20 : 25;

        // stage samp table into LDS (reuse sc buffer), coalesced
        int* samp_s = (int*)sc;
        for (int i = t; i < L * usamp; i += NTHR) samp_s[i] = samp[i];
        if (t == 0) ntop = 0;

        // ---- q, k, v projections (thread-per-row)
        if (t < L) {
            float hr[8];
#pragma unroll
            for (int e = 0; e < 8; ++e) hr[e] = h[t * 9 + e];
#pragma unroll
            for (int dd = 0; dd < 8; ++dd) {
                float aq = 0.f, ak = 0.f, av = 0.f;
#pragma unroll
                for (int e = 0; e < 8; ++e) {
                    aq += hr[e] * qw[e * 8 + dd];
                    ak += hr[e] * kw[e * 8 + dd];
                    av += hr[e] * vw[e * 8 + dd];
                }
                qs[t * 9 + dd] = aq + qb[dd];
                ks[t * 9 + dd] = ak + kb[dd];
                vs[t * 9 + dd] = av + vb[dd];
            }
        }
        __syncthreads();

        // ---- sparsity measure M[l] = max_j(q.k_samp) - mean_j(q.k_samp),
        //      published immediately as an order-preserving sortable key
        if (t < L) {
            float qr[8];
#pragma unroll
            for (int e = 0; e < 8; ++e) qr[e] = qs[t * 9 + e];
            float mx = -INFINITY, sum = 0.f;
            for (int j = 0; j < usamp; ++j) {
                int idx = samp_s[t * usamp + j];
                float acc = 0.f;
#pragma unroll
                for (int e = 0; e < 8; ++e) acc += qr[e] * ks[idx * 9 + e];
                mx = fmaxf(mx, acc);
                sum += acc;
            }
            float M = mx - sum / (float)usamp;
            unsigned ub = __float_as_uint(M);
            ub = (ub & 0x80000000u) ? ~ub : (ub | 0x80000000u);   // order-preserving
            keys[t] = ((unsigned long long)ub << 32)
                    | (unsigned long long)(0xFFFFFFFFu - (unsigned)t); // tie -> lower idx
        }
        __syncthreads();

        // ---- rank-select top-u: rank(l) = #{j: key[j] > key[l]}; selected iff rank < u.
        //      Keys are all distinct (index tiebreaker) -> exactly u selected.
        //      Slot order is irrelevant: upd[j] <-> topi[j] stays consistent.
        if (t < L) {
            const unsigned long long mykey = keys[t];
            int rank = 0;
            for (int j = 0; j < L; ++j) rank += (keys[j] > mykey) ? 1 : 0;
            int sj = -1;
            if (rank < u) {
                sj = atomicAdd(&ntop, 1);
                topi[sj] = t;
            }
            sel[t] = sj;
        }
        __syncthreads();

        // ---- full attention scores for selected queries: sc[j][l]
        if (t < L) {
            float kr[8];
#pragma unroll
            for (int e = 0; e < 8; ++e) kr[e] = ks[t * 9 + e];
            for (int j = 0; j < u; ++j) {
                int r = topi[j];
                float acc = 0.f;
#pragma unroll
                for (int e = 0; e < 8; ++e) acc += qs[r * 9 + e] * kr[e];
                sc[j * 149 + t] = acc * 0.35355339059327373f;   // * 1/sqrt(8)
            }
        }
        __syncthreads();

        // ---- softmax stats per selected row (8-lane group per j)
        {
            int g = t >> 3, lg = t & 7;
            if (g < u) {
                float mx = -INFINITY;
                for (int l = lg; l < L; l += 8) mx = fmaxf(mx, sc[g * 149 + l]);
#pragma unroll
                for (int o = 4; o; o >>= 1) mx = fmaxf(mx, __shfl_xor(mx, o));
                float sm = 0.f;
                for (int l = lg; l < L; l += 8) sm += __expf(sc[g * 149 + l] - mx);
#pragma unroll
                for (int o = 4; o; o >>= 1) sm += __shfl_xor(sm, o);
                if (lg == 0) { smax[g] = mx; ssum[g] = sm; }
            }
        }
        __syncthreads();

        // ---- normalize attn in place; compute v-mean with spare threads
        if (t < L) {
            for (int j = 0; j < u; ++j)
                sc[j * 149 + t] = __expf(sc[j * 149 + t] - smax[j]) / ssum[j];
        }
        if (t >= 248) {
            int dd = t - 248;
            float acc = 0.f;
            for (int l = 0; l < L; ++l) acc += vs[l * 9 + dd];
            vmean[dd] = acc / (float)L;
        }
        __syncthreads();

        // ---- upd[j] = attn[j] @ v   (thread per (j,d))
        if (t < u * 8) {
            int j = t >> 3, dd = t & 7;
            float acc = 0.f;
            for (int l = 0; l < L; ++l) acc += sc[j * 149 + l] * vs[l * 9 + dd];
            upd[j * 9 + dd] = acc;
        }
        __syncthreads();

        // ---- ctx -> @ow+ob -> residual+LN1 -> FF -> residual+LN2 (all per-row)
        if (t < L) {
            float ctx[8];
            int sj = sel[t];
            if (sj >= 0) {
#pragma unroll
                for (int e = 0; e < 8; ++e) ctx[e] = upd[sj * 9 + e];
            } else {
#pragma unroll
                for (int e = 0; e < 8; ++e) ctx[e] = vmean[e];
            }
            float xr[8];
#pragma unroll
            for (int dd = 0; dd < 8; ++dd) {
                float acc = 0.f;
#pragma unroll
                for (int e = 0; e < 8; ++e) acc += ctx[e] * ow[e * 8 + dd];
                xr[dd] = h[t * 9 + dd] + (acc + ob[dd]);
            }
            float mean = 0.f;
#pragma unroll
            for (int e = 0; e < 8; ++e) mean += xr[e];
            mean *= 0.125f;
            float var = 0.f;
#pragma unroll
            for (int e = 0; e < 8; ++e) { float z = xr[e] - mean; var += z * z; }
            var *= 0.125f;
            float inv = 1.0f / sqrtf(var + 1e-5f);
            float y[8];
#pragma unroll
            for (int e = 0; e < 8; ++e) y[e] = (xr[e] - mean) * inv * g1[e] + bb1[e];

            float f1[12];
#pragma unroll
            for (int o = 0; o < 12; ++o) {
                float acc = 0.f;
#pragma unroll
                for (int e = 0; e < 8; ++e) acc += y[e] * f1w[e * 12 + o];
                f1[o] = fmaxf(acc + f1b[o], 0.f);
            }
            float x2[8];
#pragma unroll
            for (int o = 0; o < 8; ++o) {
                float acc = 0.f;
#pragma unroll
                for (int e = 0; e < 12; ++e) acc += f1[e] * f2w[e * 8 + o];
                x2[o] = y[o] + (acc + f2b[o]);
            }
            mean = 0.f;
#pragma unroll
            for (int e = 0; e < 8; ++e) mean += x2[e];
            mean *= 0.125f;
            var = 0.f;
#pragma unroll
            for (int e = 0; e < 8; ++e) { float z = x2[e] - mean; var += z * z; }
            var *= 0.125f;
            inv = 1.0f / sqrtf(var + 1e-5f);
#pragma unroll
            for (int e = 0; e < 8; ++e) h[t * 9 + e] = (x2[e] - mean) * inv * g2[e] + bb2[e];
        }
        __syncthreads();

        // ---- softpool after layers 0 and 1
        if (layer < 2) {
            const float* w1  = layer ? p.sp2w1 : p.sp1w1;
            const float* sb1 = layer ? p.sp2b1 : p.sp1b1;
            const float* w2  = layer ? p.sp2w2 : p.sp1w2;
            const float* sb2 = layer ? p.sp2b2 : p.sp1b2;
            if (t < L) {
                float yr[8];
#pragma unroll
                for (int e = 0; e < 8; ++e) yr[e] = h[t * 9 + e];
                float acc2 = 0.f;
#pragma unroll
                for (int o = 0; o < 12; ++o) {
                    float acc = 0.f;
#pragma unroll
                    for (int e = 0; e < 8; ++e) acc += yr[e] * w1[e * 12 + o];
                    acc2 += fmaxf(acc + sb1[o], 0.f) * w2[o];
                }
                ssp[t] = acc2 + sb2[0];
            }
            __syncthreads();
            int Lh = L >> 1;
            float nrow[8];
            if (t < Lh) {
                float s0 = ssp[2 * t], s1 = ssp[2 * t + 1];
                float m = fmaxf(s0, s1);
                float e0 = __expf(s0 - m), e1 = __expf(s1 - m);
                float den = e0 + e1;
                float w0 = e0 / den, w1v = e1 / den;
#pragma unroll
                for (int e = 0; e < 8; ++e)
                    nrow[e] = w0 * h[(2 * t) * 9 + e] + w1v * h[(2 * t + 1) * 9 + e];
            }
            __syncthreads();   // all reads of old h complete
            if (t < Lh) {
#pragma unroll
                for (int e = 0; e < 8; ++e) h[t * 9 + e] = nrow[e];
            }
            __syncthreads();
            L = Lh;
        }
    }

    // ---- head: (37,8) @ dr_w(8,4) -> flat 148 -> fc1(74) relu -> fc2(37) relu -> fo -> sigmoid
    if (t < 37) {
        float yr[8];
#pragma unroll
        for (int e = 0; e < 8; ++e) yr[e] = h[t * 9 + e];
#pragma unroll
        for (int c = 0; c < 4; ++c) {
            float acc = 0.f;
#pragma unroll
            for (int e = 0; e < 8; ++e) acc += yr[e] * p.dr_w[e * 4 + c];
            headf[t * 4 + c] = acc + p.dr_b[c];
        }
    }
    __syncthreads();
    if (t < 74) {
        float acc = 0.f;
        for (int i = 0; i < 148; ++i) acc += headf[i] * p.fc1w[i * 74 + t];
        ssp[t] = fmaxf(acc + p.fc1b[t], 0.f);
    }
    __syncthreads();
    if (t < 37) {
        float acc = 0.f;
        for (int i = 0; i < 74; ++i) acc += ssp[i] * p.fc2w[i * 37 + t];
        hd2[t] = fmaxf(acc + p.fc2b[t], 0.f);
    }
    __syncthreads();
    if (t == 0) {
        float acc = 0.f;
        for (int i = 0; i < 37; ++i) acc += hd2[i] * p.fow[i];
        acc += p.fob[0];
        p.out[b] = 1.f / (1.f + __expf(-acc));
    }
}

extern "C" void kernel_launch(void* const* d_in, const int* in_sizes, int n_in,
                              void* d_out, int out_size, void* d_ws, size_t ws_size,
                              hipStream_t stream) {
    Params p;
    p.x     = (const float*)d_in[0];
    p.samp1 = (const int*)d_in[1];
    p.samp2 = (const int*)d_in[2];
    p.samp3 = (const int*)d_in[3];
    p.pe_w  = (const float*)d_in[4];  p.pe_b  = (const float*)d_in[5];
    p.qw    = (const float*)d_in[6];  p.qb    = (const float*)d_in[7];
    p.kw    = (const float*)d_in[8];  p.kb    = (const float*)d_in[9];
    p.vw    = (const float*)d_in[10]; p.vb    = (const float*)d_in[11];
    p.ow    = (const float*)d_in[12]; p.ob    = (const float*)d_in[13];
    p.f1w   = (const float*)d_in[14]; p.f1b   = (const float*)d_in[15];
    p.f2w   = (const float*)d_in[16]; p.f2b   = (const float*)d_in[17];
    p.ln1g  = (const float*)d_in[18]; p.ln1b  = (const float*)d_in[19];
    p.ln2g  = (const float*)d_in[20]; p.ln2b  = (const float*)d_in[21];
    p.sp1w1 = (const float*)d_in[22]; p.sp1b1 = (const float*)d_in[23];
    p.sp1w2 = (const float*)d_in[24]; p.sp1b2 = (const float*)d_in[25];
    p.sp2w1 = (const float*)d_in[26]; p.sp2b1 = (const float*)d_in[27];
    p.sp2w2 = (const float*)d_in[28]; p.sp2b2 = (const float*)d_in[29];
    p.dr_w  = (const float*)d_in[30]; p.dr_b  = (const float*)d_in[31];
    p.fc1w  = (const float*)d_in[32]; p.fc1b  = (const float*)d_in[33];
    p.fc2w  = (const float*)d_in[34]; p.fc2b  = (const float*)d_in[35];
    p.fow   = (const float*)d_in[36]; p.fob   = (const float*)d_in[37];

    const int n = in_sizes[0];          // 4096 * 296
    const int B = n / 296;

    float* wsf   = (float*)d_ws;
    float* part  = wsf;                 // 512 floats of per-block max/min pairs
    float* scale = wsf + 512;           // 1 float: (max - min + 1e-6)

    minmax_part<<<256, 256, 0, stream>>>((const float4*)p.x, n / 4, part);
    minmax_final<<<1, 256, 0, stream>>>(part, 256, scale);

    p.scale = scale;
    p.out   = (float*)d_out;
    fused_forward<<<B, 256, 0, stream>>>(p);
}

// Round 3
// 387.999 us; speedup vs baseline: 1.0093x; 1.0093x over previous
//
#include <hip/hip_runtime.h>
#include <math.h>

#define NTHR 256

struct Params {
    const float* x;
    const int*   samp1;
    const int*   samp2;
    const int*   samp3;
    const float* pe_w; const float* pe_b;
    const float* qw; const float* qb;
    const float* kw; const float* kb;
    const float* vw; const float* vb;
    const float* ow; const float* ob;
    const float* f1w; const float* f1b;
    const float* f2w; const float* f2b;
    const float* ln1g; const float* ln1b;
    const float* ln2g; const float* ln2b;
    const float* sp1w1; const float* sp1b1; const float* sp1w2; const float* sp1b2;
    const float* sp2w1; const float* sp2b1; const float* sp2w2; const float* sp2b2;
    const float* dr_w; const float* dr_b;
    const float* fc1w; const float* fc1b;
    const float* fc2w; const float* fc2b;
    const float* fow;  const float* fob;
    const float* part;    // ws: 256 blocks x {max, min}
    float* out;
};

__global__ __launch_bounds__(256) void minmax_part(const float4* __restrict__ x4, int n4,
                                                   float* __restrict__ part) {
    float mx = -INFINITY, mn = INFINITY;
    for (int i = blockIdx.x * blockDim.x + threadIdx.x; i < n4; i += gridDim.x * blockDim.x) {
        float4 v = x4[i];
        mx = fmaxf(fmaxf(fmaxf(mx, v.x), fmaxf(v.y, v.z)), v.w);
        mn = fminf(fminf(fminf(mn, v.x), fminf(v.y, v.z)), v.w);
    }
#pragma unroll
    for (int o = 32; o; o >>= 1) {
        mx = fmaxf(mx, __shfl_xor(mx, o));
        mn = fminf(mn, __shfl_xor(mn, o));
    }
    __shared__ float smx[4], smn[4];
    if ((threadIdx.x & 63) == 0) { smx[threadIdx.x >> 6] = mx; smn[threadIdx.x >> 6] = mn; }
    __syncthreads();
    if (threadIdx.x == 0) {
        for (int w = 1; w < 4; ++w) { mx = fmaxf(mx, smx[w]); mn = fminf(mn, smn[w]); }
        part[blockIdx.x * 2]     = mx;
        part[blockIdx.x * 2 + 1] = mn;
    }
}

// One transformer layer, compile-time geometry. All row buffers stride 9
// (odd -> bijective mod 32 banks -> conflict-free strided access).
// region (13*149 floats) time-shares: keys (rank phase) -> scores (attn) ->
// softpool scores / head buffers.
template<int L, int USAMP, int U, bool POOL>
__device__ __forceinline__ void layer_fn(
    const int t,
    float* __restrict__ h, float* __restrict__ ks, float* __restrict__ vs,
    float* __restrict__ region, float* __restrict__ q_sel, float* __restrict__ upd,
    float* __restrict__ smax, float* __restrict__ ssum, float* __restrict__ vmean,
    int* __restrict__ ntop,
    const float* qw, const float* qb, const float* kw, const float* kb,
    const float* vw, const float* vb, const float* ow, const float* ob,
    const float* f1w, const float* f1b, const float* f2w, const float* f2b,
    const float* g1, const float* bb1, const float* g2, const float* bb2,
    const int* __restrict__ samp,
    const float* spw1, const float* spb1, const float* spw2, const float* spb2)
{
    float* sc = region;
    unsigned long long* keys = (unsigned long long*)region;

    if (t == 0) *ntop = 0;

    float hr[8], qr[8];
    // ---- projections: k,v -> LDS; q stays in registers
    if (t < L) {
#pragma unroll
        for (int e = 0; e < 8; ++e) hr[e] = h[t * 9 + e];
#pragma unroll
        for (int dd = 0; dd < 8; ++dd) {
            float aq = 0.f, ak = 0.f, av = 0.f;
#pragma unroll
            for (int e = 0; e < 8; ++e) {
                aq += hr[e] * qw[e * 8 + dd];
                ak += hr[e] * kw[e * 8 + dd];
                av += hr[e] * vw[e * 8 + dd];
            }
            qr[dd] = aq + qb[dd];
            ks[t * 9 + dd] = ak + kb[dd];
            vs[t * 9 + dd] = av + vb[dd];
        }
    }
    __syncthreads();

    // ---- sparsity measure -> sortable key (samp read direct from global: single-use)
    if (t < L) {
        const int* srow = samp + t * USAMP;
        float mx = -INFINITY, sum = 0.f;
        for (int j = 0; j < USAMP; ++j) {
            int idx = srow[j];
            float acc = 0.f;
#pragma unroll
            for (int e = 0; e < 8; ++e) acc += qr[e] * ks[idx * 9 + e];
            mx = fmaxf(mx, acc);
            sum += acc;
        }
        float M = mx - sum / (float)USAMP;
        unsigned ub = __float_as_uint(M);
        ub = (ub & 0x80000000u) ? ~ub : (ub | 0x80000000u);     // order-preserving
        keys[t] = ((unsigned long long)ub << 32)
                | (unsigned long long)(0xFFFFFFFFu - (unsigned)t);  // tie -> lower idx
    }
    __syncthreads();

    // ---- rank-select top-U (keys distinct -> exactly U selected);
    //      selected threads publish their own q row (slot in register sj)
    int sj = -1;
    if (t < L) {
        const unsigned long long mykey = keys[t];
        int rank = 0;
#pragma unroll 16
        for (int j = 0; j < L; ++j) rank += (keys[j] > mykey) ? 1 : 0;
        if (rank < U) {
            sj = atomicAdd(ntop, 1);
#pragma unroll
            for (int e = 0; e < 8; ++e) q_sel[sj * 9 + e] = qr[e];
        }
    }
    __syncthreads();

    // ---- attention over selected rows in chunks of <=13 (keeps sc at 13x149)
#pragma unroll
    for (int c0 = 0; c0 < U; c0 += 13) {
        const int cn = (U - c0) < 13 ? (U - c0) : 13;

        // scores sc[j][l]
        if (t < L) {
            float kr[8];
#pragma unroll
            for (int e = 0; e < 8; ++e) kr[e] = ks[t * 9 + e];
#pragma unroll
            for (int j = 0; j < cn; ++j) {
                float acc = 0.f;
#pragma unroll
                for (int e = 0; e < 8; ++e) acc += q_sel[(c0 + j) * 9 + e] * kr[e];
                sc[j * 149 + t] = acc * 0.35355339059327373f;   // * 1/sqrt(8)
            }
        }
        if (c0 == 0 && t >= 248) {          // v-mean on spare threads, once per layer
            int dd = t - 248;
            float acc = 0.f;
#pragma unroll 4
            for (int l = 0; l < L; ++l) acc += vs[l * 9 + dd];
            vmean[dd] = acc / (float)L;
        }
        __syncthreads();

        // softmax stats per row (8-lane group per j)
        {
            int g = t >> 3, lg = t & 7;
            if (g < cn) {
                float mx = -INFINITY;
                for (int l = lg; l < L; l += 8) mx = fmaxf(mx, sc[g * 149 + l]);
#pragma unroll
                for (int o = 4; o; o >>= 1) mx = fmaxf(mx, __shfl_xor(mx, o));
                float sm = 0.f;
                for (int l = lg; l < L; l += 8) sm += __expf(sc[g * 149 + l] - mx);
#pragma unroll
                for (int o = 4; o; o >>= 1) sm += __shfl_xor(sm, o);
                if (lg == 0) { smax[g] = mx; ssum[g] = sm; }
            }
        }
        __syncthreads();

        // normalize in place
        if (t < L) {
#pragma unroll
            for (int j = 0; j < cn; ++j)
                sc[j * 149 + t] = __expf(sc[j * 149 + t] - smax[j]) / ssum[j];
        }
        __syncthreads();

        // upd[c0+j] = attn[j] @ v  (2 accumulators for ILP)
        if (t < cn * 8) {
            int j = t >> 3, dd = t & 7;
            float a0 = 0.f, a1 = 0.f;
#pragma unroll 8
            for (int l = 0; l < (L & ~1); l += 2) {
                a0 += sc[j * 149 + l]     * vs[l * 9 + dd];
                a1 += sc[j * 149 + l + 1] * vs[(l + 1) * 9 + dd];
            }
            float a = a0 + a1;
            if (L & 1) a += sc[j * 149 + (L - 1)] * vs[(L - 1) * 9 + dd];
            upd[(c0 + j) * 9 + dd] = a;
        }
        __syncthreads();
    }

    // ---- ctx -> @ow+ob -> residual+LN1 -> FF -> residual+LN2 (+softpool score fused)
    if (t < L) {
        float ctx[8];
        if (sj >= 0) {
#pragma unroll
            for (int e = 0; e < 8; ++e) ctx[e] = upd[sj * 9 + e];
        } else {
#pragma unroll
            for (int e = 0; e < 8; ++e) ctx[e] = vmean[e];
        }
        float xr[8];
#pragma unroll
        for (int dd = 0; dd < 8; ++dd) {
            float acc = 0.f;
#pragma unroll
            for (int e = 0; e < 8; ++e) acc += ctx[e] * ow[e * 8 + dd];
            xr[dd] = hr[dd] + (acc + ob[dd]);
        }
        float mean = 0.f;
#pragma unroll
        for (int e = 0; e < 8; ++e) mean += xr[e];
        mean *= 0.125f;
        float var = 0.f;
#pragma unroll
        for (int e = 0; e < 8; ++e) { float z = xr[e] - mean; var += z * z; }
        var *= 0.125f;
        float inv = 1.0f / sqrtf(var + 1e-5f);
        float y[8];
#pragma unroll
        for (int e = 0; e < 8; ++e) y[e] = (xr[e] - mean) * inv * g1[e] + bb1[e];

        float f1[12];
#pragma unroll
        for (int o = 0; o < 12; ++o) {
            float acc = 0.f;
#pragma unroll
            for (int e = 0; e < 8; ++e) acc += y[e] * f1w[e * 12 + o];
            f1[o] = fmaxf(acc + f1b[o], 0.f);
        }
        float x2[8];
#pragma unroll
        for (int o = 0; o < 8; ++o) {
            float acc = 0.f;
#pragma unroll
            for (int e = 0; e < 12; ++e) acc += f1[e] * f2w[e * 8 + o];
            x2[o] = y[o] + (acc + f2b[o]);
        }
        mean = 0.f;
#pragma unroll
        for (int e = 0; e < 8; ++e) mean += x2[e];
        mean *= 0.125f;
        var = 0.f;
#pragma unroll
        for (int e = 0; e < 8; ++e) { float z = x2[e] - mean; var += z * z; }
        var *= 0.125f;
        inv = 1.0f / sqrtf(var + 1e-5f);
        float y2[8];
#pragma unroll
        for (int e = 0; e < 8; ++e) {
            y2[e] = (x2[e] - mean) * inv * g2[e] + bb2[e];
            h[t * 9 + e] = y2[e];
        }

        if (POOL) {   // softpool score from registers (no h reread)
            float acc2 = 0.f;
#pragma unroll
            for (int o = 0; o < 12; ++o) {
                float acc = 0.f;
#pragma unroll
                for (int e = 0; e < 8; ++e) acc += y2[e] * spw1[e * 12 + o];
                acc2 += fmaxf(acc + spb1[o], 0.f) * spw2[o];
            }
            region[t] = acc2 + spb2[0];     // sc region is dead now
        }
    }
    __syncthreads();

    // ---- softpool combine
    if (POOL) {
        constexpr int Lh = L / 2;
        float nrow[8];
        float w0 = 0.f, w1v = 0.f;
        if (t < Lh) {
            float s0 = region[2 * t], s1 = region[2 * t + 1];
            float m = fmaxf(s0, s1);
            float e0 = __expf(s0 - m), e1 = __expf(s1 - m);
            float den = e0 + e1;
            w0 = e0 / den; w1v = e1 / den;
#pragma unroll
            for (int e = 0; e < 8; ++e)
                nrow[e] = w0 * h[(2 * t) * 9 + e] + w1v * h[(2 * t + 1) * 9 + e];
        }
        __syncthreads();   // all reads of old h complete
        if (t < Lh) {
#pragma unroll
            for (int e = 0; e < 8; ++e) h[t * 9 + e] = nrow[e];
        }
        __syncthreads();
    }
}

__global__ __launch_bounds__(256, 6) void fused_forward(Params p) {
    const int b = blockIdx.x;
    const int t = threadIdx.x;

    __shared__ float h [148 * 9];
    __shared__ float ks[148 * 9];
    __shared__ float vs[148 * 9];
    __shared__ __align__(16) float region[13 * 149];   // keys / scores / softpool / head
    __shared__ float q_sel[25 * 9];
    __shared__ float upd[25 * 9];
    __shared__ float smax[13], ssum[13];
    __shared__ float vmean[8];
    __shared__ int   ntop;
    __shared__ float scale_s;
    __shared__ float smx[4], smn[4];

    // ---- global-scale reduce (folds old minmax_final kernel): part has 256x{mx,mn}
    {
        float mx = p.part[2 * t], mn = p.part[2 * t + 1];
#pragma unroll
        for (int o = 32; o; o >>= 1) {
            mx = fmaxf(mx, __shfl_xor(mx, o));
            mn = fminf(mn, __shfl_xor(mn, o));
        }
        if ((t & 63) == 0) { smx[t >> 6] = mx; smn[t >> 6] = mn; }
        __syncthreads();
        if (t == 0) {
            for (int w = 1; w < 4; ++w) { mx = fmaxf(mx, smx[w]); mn = fminf(mn, smn[w]); }
            scale_s = mx - mn + 1e-6f;
        }
        __syncthreads();
    }
    const float dscale = scale_s;

    // ---- preprocess: pair-mean of [x, x/scale], sin/cos pe, @pe_w + pe_b
    if (t < 148) {
        const float2 xp = ((const float2*)(p.x + b * 296))[t];
        float pin[4];
        pin[0] = 0.5f * (xp.x + xp.y);
        pin[1] = 0.5f * (xp.x / dscale + xp.y / dscale);
        pin[2] = sinf((float)t);
        pin[3] = cosf((float)t);
#pragma unroll
        for (int dd = 0; dd < 8; ++dd) {
            float acc = 0.f;
#pragma unroll
            for (int e = 0; e < 4; ++e) acc += pin[e] * p.pe_w[e * 8 + dd];
            h[t * 9 + dd] = acc + p.pe_b[dd];
        }
    }
    __syncthreads();

    layer_fn<148, 25, 25, true >(t, h, ks, vs, region, q_sel, upd, smax, ssum, vmean, &ntop,
        p.qw,       p.qb,      p.kw,       p.kb,      p.vw,       p.vb,      p.ow,       p.ob,
        p.f1w,      p.f1b,     p.f2w,      p.f2b,
        p.ln1g,     p.ln1b,    p.ln2g,     p.ln2b,    p.samp1,
        p.sp1w1, p.sp1b1, p.sp1w2, p.sp1b2);
    layer_fn<74, 25, 25, true >(t, h, ks, vs, region, q_sel, upd, smax, ssum, vmean, &ntop,
        p.qw + 64,  p.qb + 8,  p.kw + 64,  p.kb + 8,  p.vw + 64,  p.vb + 8,  p.ow + 64,  p.ob + 8,
        p.f1w + 96, p.f1b + 12, p.f2w + 96, p.f2b + 8,
        p.ln1g + 8, p.ln1b + 8, p.ln2g + 8, p.ln2b + 8, p.samp2,
        p.sp2w1, p.sp2b1, p.sp2w2, p.sp2b2);
    layer_fn<37, 20, 20, false>(t, h, ks, vs, region, q_sel, upd, smax, ssum, vmean, &ntop,
        p.qw + 128, p.qb + 16, p.kw + 128, p.kb + 16, p.vw + 128, p.vb + 16, p.ow + 128, p.ob + 16,
        p.f1w + 192, p.f1b + 24, p.f2w + 192, p.f2b + 16,
        p.ln1g + 16, p.ln1b + 16, p.ln2g + 16, p.ln2b + 16, p.samp3,
        nullptr, nullptr, nullptr, nullptr);

    // ---- head: (37,8)@dr_w(8,4) -> flat 148 -> fc1(74) relu -> fc2(37) relu -> fo -> sigmoid
    float* hf  = region + 256;   // 148 floats
    float* s1b = region;         // 74 floats
    float* hd2 = region + 512;   // 37 floats
    if (t < 37) {
        float yr[8];
#pragma unroll
        for (int e = 0; e < 8; ++e) yr[e] = h[t * 9 + e];
#pragma unroll
        for (int c = 0; c < 4; ++c) {
            float acc = 0.f;
#pragma unroll
            for (int e = 0; e < 8; ++e) acc += yr[e] * p.dr_w[e * 4 + c];
            hf[t * 4 + c] = acc + p.dr_b[c];
        }
    }
    __syncthreads();
    if (t < 74) {
        float acc = 0.f;
#pragma unroll 4
        for (int i = 0; i < 148; ++i) acc += hf[i] * p.fc1w[i * 74 + t];
        s1b[t] = fmaxf(acc + p.fc1b[t], 0.f);
    }
    __syncthreads();
    if (t < 37) {
        float acc = 0.f;
#pragma unroll 2
        for (int i = 0; i < 74; ++i) acc += s1b[i] * p.fc2w[i * 37 + t];
        hd2[t] = fmaxf(acc + p.fc2b[t], 0.f);
    }
    __syncthreads();
    if (t == 0) {
        float acc = 0.f;
        for (int i = 0; i < 37; ++i) acc += hd2[i] * p.fow[i];
        acc += p.fob[0];
        p.out[b] = 1.f / (1.f + __expf(-acc));
    }
}

extern "C" void kernel_launch(void* const* d_in, const int* in_sizes, int n_in,
                              void* d_out, int out_size, void* d_ws, size_t ws_size,
                              hipStream_t stream) {
    Params p;
    p.x     = (const float*)d_in[0];
    p.samp1 = (const int*)d_in[1];
    p.samp2 = (const int*)d_in[2];
    p.samp3 = (const int*)d_in[3];
    p.pe_w  = (const float*)d_in[4];  p.pe_b  = (const float*)d_in[5];
    p.qw    = (const float*)d_in[6];  p.qb    = (const float*)d_in[7];
    p.kw    = (const float*)d_in[8];  p.kb    = (const float*)d_in[9];
    p.vw    = (const float*)d_in[10]; p.vb    = (const float*)d_in[11];
    p.ow    = (const float*)d_in[12]; p.ob    = (const float*)d_in[13];
    p.f1w   = (const float*)d_in[14]; p.f1b   = (const float*)d_in[15];
    p.f2w   = (const float*)d_in[16]; p.f2b   = (const float*)d_in[17];
    p.ln1g  = (const float*)d_in[18]; p.ln1b  = (const float*)d_in[19];
    p.ln2g  = (const float*)d_in[20]; p.ln2b  = (const float*)d_in[21];
    p.sp1w1 = (const float*)d_in[22]; p.sp1b1 = (const float*)d_in[23];
    p.sp1w2 = (const float*)d_in[24]; p.sp1b2 = (const float*)d_in[25];
    p.sp2w1 = (const float*)d_in[26]; p.sp2b1 = (const float*)d_in[27];
    p.sp2w2 = (const float*)d_in[28]; p.sp2b2 = (const float*)d_in[29];
    p.dr_w  = (const float*)d_in[30]; p.dr_b  = (const float*)d_in[31];
    p.fc1w  = (const float*)d_in[32]; p.fc1b  = (const float*)d_in[33];
    p.fc2w  = (const float*)d_in[34]; p.fc2b  = (const float*)d_in[35];
    p.fow   = (const float*)d_in[36]; p.fob   = (const float*)d_in[37];

    const int n = in_sizes[0];          // 4096 * 296
    const int B = n / 296;

    float* part = (float*)d_ws;         // 512 floats: 256 blocks x {max, min}

    minmax_part<<<256, 256, 0, stream>>>((const float4*)p.x, n / 4, part);

    p.part = part;
    p.out  = (float*)d_out;
    fused_forward<<<B, 256, 0, stream>>>(p);
}